// Round 7
// baseline (628.343 us; speedup 1.0000x reference)
//
#include <hip/hip_runtime.h>
#include <hip/hip_bf16.h>

// Problem constants (from reference): N=100000, IN=512, OUT=256, E=3200000
#define IN_DIM  512
#define OUT_DIM 256

// Bucket-sort parameters for the SpMM edge pipeline.
// bucket = row >> 6  (64 rows/bucket, 1563 buckets for N=100000)
// Edges/bucket ~ Binomial(3.2e6, 64/1e5): mean 2048, sigma 45. BCAP = mean + 8.5*sigma.
#define RPB     64
#define MAXNB   1600
#define BCAP    2432
#define SCHUNK  6400    // 500 blocks -> 2 blocks/CU

using bf16x8 = __attribute__((ext_vector_type(8))) __bf16;
using f32x4  = __attribute__((ext_vector_type(4))) float;

__device__ __forceinline__ void async_lds16(const void* g, void* l) {
    __builtin_amdgcn_global_load_lds(
        (const __attribute__((address_space(1))) void*)g,
        (__attribute__((address_space(3))) void*)l, 16, 0, 0);
}

// exp-based tanh: 1 - 2/(e^{2v}+1). Saturates correctly at +-inf, err ~1e-5 << bf16
// storage rounding. Replaces libm tanhf on 25.6M elements.
__device__ __forceinline__ float fast_tanh(float v) {
    float e = __expf(2.0f * v);
    return 1.0f - 2.0f / (e + 1.0f);
}

// --- Kernel 1: W[512][256] f32 -> Wt[256][512] bf16 (transposed, for B-frag rows) ---
__global__ void convert_weight(const float* __restrict__ W, __bf16* __restrict__ Wt) {
    int idx = blockIdx.x * blockDim.x + threadIdx.x;   // 0..131071
    int n = idx >> 9;          // out col
    int k = idx & 511;         // in dim
    Wt[idx] = (__bf16)W[k * OUT_DIM + n];
}

// --- Kernel 2: support = tanh(x @ W) in bf16 ---
// R7: A-loads SOFTWARE-PIPELINED one K-step ahead. Previously each step began with a
// dependent HBM load of x (205 MB stream, always cold, ~900 cyc) consumed immediately:
// the kernel was ~pure exposed load latency (total MFMA work is only ~3 us/CU).
// Now step kk+1's loads issue before step kk's MFMAs; the register copy at the bottom
// of the loop carries the vmcnt wait, so latency hides under MFMA + next barrier drain.
// A-loads are non-temporal: x is a pure stream (each row read once) -- 100% L2 pollution.
__launch_bounds__(512)
__global__ void gemm_tanh(const float* __restrict__ x, const __bf16* __restrict__ Wt,
                          __hip_bfloat16* __restrict__ support, const int* __restrict__ active,
                          int N) {
    __shared__ __bf16 Bt[2][256 * 32];   // [buf][n][32 k] bf16, 2 x 16 KB

    const int tid  = threadIdx.x;
    const int wave = tid >> 6;      // 0..7
    const int lane = tid & 63;
    const int m    = lane & 15;     // A row / B col / C col
    const int quad = lane >> 4;     // k-block selector, C row-block

    int r0 = blockIdx.x * 128 + wave * 16;
    if (r0 + 16 > N) r0 = N - 16;   // clamp (duplicate work, identical values; keeps barriers uniform)

    const float* abase = x + (size_t)(r0 + m) * IN_DIM + quad * 8;
    const char* WtB = (const char*)Wt;

    f32x4 acc[16];
#pragma unroll
    for (int t = 0; t < 16; ++t) acc[t] = (f32x4)0.0f;

    // prefetch B k-slice 0 into buf 0: idx = j*512+tid in [0,1024); n=idx>>2, kp=idx&3
    {
#pragma unroll
        for (int j = 0; j < 2; ++j) {
            int idx = j * 512 + tid;
            int n = idx >> 2, kp = idx & 3;
            async_lds16(WtB + (size_t)n * 1024 + kp * 16,
                        (char*)&Bt[0][0] + idx * 16);
        }
    }

    // prefetch A step 0
    f32x4 a0 = __builtin_nontemporal_load((const f32x4*)abase);
    f32x4 a1 = __builtin_nontemporal_load((const f32x4*)abase + 1);

    int cur = 0;
    for (int kk = 0; kk < 16; ++kk) {
        __syncthreads();   // drains vmcnt -> Bt[cur] ready
        if (kk + 1 < 16) {
            const int k0n = (kk + 1) * 32;
#pragma unroll
            for (int j = 0; j < 2; ++j) {
                int idx = j * 512 + tid;
                int n = idx >> 2, kp = idx & 3;
                async_lds16(WtB + (size_t)n * 1024 + k0n * 2 + kp * 16,
                            (char*)&Bt[cur ^ 1][0] + idx * 16);
            }
        }

        // issue A-loads for step kk+1 BEFORE consuming step kk's (prefetch pipeline)
        f32x4 a0n, a1n;
        if (kk + 1 < 16) {
            const f32x4* apn = (const f32x4*)(abase + (kk + 1) * 32);
            a0n = __builtin_nontemporal_load(apn);
            a1n = __builtin_nontemporal_load(apn + 1);
        }

        bf16x8 af;
        af[0] = (__bf16)a0[0]; af[1] = (__bf16)a0[1]; af[2] = (__bf16)a0[2]; af[3] = (__bf16)a0[3];
        af[4] = (__bf16)a1[0]; af[5] = (__bf16)a1[1]; af[6] = (__bf16)a1[2]; af[7] = (__bf16)a1[3];

#pragma unroll
        for (int t = 0; t < 16; ++t) {
            bf16x8 bf = *(const bf16x8*)&Bt[cur][(t * 16 + m) * 32 + quad * 8];
            acc[t] = __builtin_amdgcn_mfma_f32_16x16x32_bf16(af, bf, acc[t], 0, 0, 0);
        }

        if (kk + 1 < 16) { a0 = a0n; a1 = a1n; }   // vmcnt wait lands here, after MFMAs
        cur ^= 1;
    }

    const int act = active[0];
    const int row_base = r0 + quad * 4;
#pragma unroll
    for (int t = 0; t < 16; ++t) {
#pragma unroll
        for (int r = 0; r < 4; ++r) {
            float v = acc[t][r];
            if (act) v = fast_tanh(v);
            support[(size_t)(row_base + r) * OUT_DIM + t * 16 + m] = __float2bfloat16(v);
        }
    }
}

// --- Kernel 3: bucket scatter --- (unchanged from R6)
__launch_bounds__(512)
__global__ void bucket_scatter(const int* __restrict__ rows, const int* __restrict__ cols,
                               const float* __restrict__ vals, int* __restrict__ gcur,
                               unsigned long long* __restrict__ sorted, int E, int nb) {
    __shared__ unsigned long long buf[SCHUNK];   // 51.2 KB
    __shared__ int lbase[MAXNB];                 // exclusive prefix (P5 src base)
    __shared__ int lcur[MAXNB];                  // P1: counts -> P2: excl -> P3: cursor
    __shared__ int gbase_s[MAXNB];
    __shared__ int wtot[8], woff[8];

    const int tid  = threadIdx.x;
    const int w    = tid >> 6;
    const int ln   = tid & 63;
    const int e0   = blockIdx.x * SCHUNK;
    const int n    = min(SCHUNK, E - e0);

    for (int i = tid; i < nb; i += 512) lcur[i] = 0;
    __syncthreads();

    // P1: local bucket histogram (into lcur)
    for (int i = tid; i < n; i += 512)
        atomicAdd(&lcur[rows[e0 + i] >> 6], 1);
    __syncthreads();

    // P2a: per-wave range totals (wave w owns bins [w*256, min(nb,(w+1)*256)))
    {
        const int lo = w * 256, hi = min(nb, lo + 256);
        int sum = 0;
        for (int i = lo + ln; i < hi; i += 64) sum += lcur[i];
#pragma unroll
        for (int d = 32; d > 0; d >>= 1) sum += __shfl_down(sum, d);
        if (ln == 0) wtot[w] = sum;
    }
    __syncthreads();
    if (tid == 0) {
        int acc = 0;
#pragma unroll
        for (int i = 0; i < 8; ++i) { woff[i] = acc; acc += wtot[i]; }
    }
    __syncthreads();
    // P2b: per-wave exclusive scan of its range, offset by woff
    {
        const int lo = w * 256, hi = min(nb, lo + 256);
        int carry = woff[w];
        for (int base = lo; base < hi; base += 64) {
            int i = base + ln;
            int v = (i < hi) ? lcur[i] : 0;
            int pref = v;
#pragma unroll
            for (int d = 1; d < 64; d <<= 1) {
                int up = __shfl_up(pref, d, 64);
                if (ln >= d) pref += up;
            }
            if (i < hi) { int ex = carry + pref - v; lbase[i] = ex; lcur[i] = ex; }
            carry += __shfl(pref, 63, 64);
        }
    }
    __syncthreads();

    // P3: scatter packed entries into LDS, bucket-sorted (edge re-read is L2-hot)
    for (int i = tid; i < n; i += 512) {
        int r = rows[e0 + i];
        int b = r >> 6;
        unsigned int low = (unsigned int)cols[e0 + i] | (((unsigned int)(r & 63)) << 17);
        unsigned long long packed = (unsigned long long)low |
            ((unsigned long long)(unsigned int)__float_as_int(vals[e0 + i]) << 32);
        int pos = atomicAdd(&lcur[b], 1);
        buf[pos] = packed;
    }
    __syncthreads();

    // P4: reserve global space, all buckets in parallel (hide atomic latency)
    for (int b = tid; b < nb; b += 512) {
        int c = lcur[b] - lbase[b];
        gbase_s[b] = c ? atomicAdd(&gcur[b], c) : 0;
    }
    __syncthreads();

    // P5: 4-lane-group cooperative contiguous copy LDS -> global (runs avg 4 entries)
    const int g = tid >> 2, l4 = tid & 3;    // 128 groups x 4 lanes
    for (int b = g; b < nb; b += 128) {
        int c = lcur[b] - lbase[b];
        if (c == 0) continue;
        int gb = gbase_s[b];
        int lim = BCAP - gb;                 // overflow guard (statistically never fires)
        if (c > lim) c = (lim > 0) ? lim : 0;
        int src = lbase[b];
        unsigned long long* dst = sorted + (size_t)b * BCAP + gb;
        for (int j = l4; j < c; j += 4) dst[j] = buf[src + j];
    }
}

// --- Kernel 4: per-bucket accumulate --- (unchanged from R5/R6; at its gather plateau:
// support (51 MB) >> per-XCD L2 (4 MB) -> ~750 MB L2-miss traffic at ~3.2 TB/s.
// R2: occupancy doesn't help; R4: access order doesn't help.)
__launch_bounds__(256)
__global__ void bucket_accumulate(const unsigned short* __restrict__ support,
                                  const int* __restrict__ gcur,
                                  const unsigned long long* __restrict__ sorted,
                                  float* __restrict__ out, int N) {
    __shared__ unsigned long long raw[BCAP];   // 19.5 KB (staged once, coalesced)
    __shared__ unsigned long long seg[BCAP];   // 19.5 KB (row-sorted)
    __shared__ int rowstart[RPB + 1];
    __shared__ int rcur[RPB];

    const int b   = blockIdx.x;
    const int tid = threadIdx.x;
    const int r0  = b * RPB;

    int scnt = gcur[b];
    if (scnt > BCAP) scnt = BCAP;             // safety clamp
    const size_t s0 = (size_t)b * BCAP;

    // P0: stage segment into LDS (single global read)
    for (int i = tid; i < scnt; i += 256) raw[i] = sorted[s0 + i];
    if (tid < RPB) rcur[tid] = 0;
    __syncthreads();

    // P1: per-row histogram from LDS
    for (int i = tid; i < scnt; i += 256)
        atomicAdd(&rcur[(int)((raw[i] >> 17) & 63)], 1);
    __syncthreads();

    // P2: exclusive prefix over 64 rows (wave 0)
    if (tid < 64) {
        int v = rcur[tid];
        int pref = v;
#pragma unroll
        for (int d = 1; d < 64; d <<= 1) {
            int up = __shfl_up(pref, d, 64);
            if (tid >= d) pref += up;
        }
        int ex = pref - v;
        rowstart[tid] = ex;
        rcur[tid]     = ex;
    }
    if (tid == 0) rowstart[RPB] = scnt;
    __syncthreads();

    // P3: LDS->LDS counting-sort scatter
    for (int i = tid; i < scnt; i += 256) {
        unsigned long long p = raw[i];
        int rib = (int)((p >> 17) & 63);
        int pos = atomicAdd(&rcur[rib], 1);
        seg[pos] = p;
    }
    __syncthreads();

    // P4: one wave per row; 8-deep unrolled gather/FMA (8 outstanding loads/wave)
    const int wave = tid >> 6, lane = tid & 63;
    const uint2* supb = (const uint2*)support;     // row stride = 64 uint2
    for (int k = 0; k < 16; ++k) {
        int rib = wave * 16 + k;
        int r = r0 + rib;
        if (r >= N) break;
        int e   = rowstart[rib];
        int end = rowstart[rib + 1];

        float a0 = 0.f, a1 = 0.f, a2 = 0.f, a3 = 0.f;

        for (; e + 8 <= end; e += 8) {
            unsigned long long pp[8];
#pragma unroll
            for (int j = 0; j < 8; ++j) pp[j] = seg[e + j];
            uint2 uu[8];
#pragma unroll
            for (int j = 0; j < 8; ++j) {
                int c = (int)(pp[j] & 0x1FFFF);
                uu[j] = supb[((size_t)c << 6) + lane];
            }
#pragma unroll
            for (int j = 0; j < 8; ++j) {
                float v = __uint_as_float((unsigned int)(pp[j] >> 32));
                a0 = fmaf(v, __uint_as_float(uu[j].x << 16),          a0);
                a1 = fmaf(v, __uint_as_float(uu[j].x & 0xffff0000u),  a1);
                a2 = fmaf(v, __uint_as_float(uu[j].y << 16),          a2);
                a3 = fmaf(v, __uint_as_float(uu[j].y & 0xffff0000u),  a3);
            }
        }
        for (; e + 4 <= end; e += 4) {
            unsigned long long pp[4];
#pragma unroll
            for (int j = 0; j < 4; ++j) pp[j] = seg[e + j];
            uint2 uu[4];
#pragma unroll
            for (int j = 0; j < 4; ++j) {
                int c = (int)(pp[j] & 0x1FFFF);
                uu[j] = supb[((size_t)c << 6) + lane];
            }
#pragma unroll
            for (int j = 0; j < 4; ++j) {
                float v = __uint_as_float((unsigned int)(pp[j] >> 32));
                a0 = fmaf(v, __uint_as_float(uu[j].x << 16),          a0);
                a1 = fmaf(v, __uint_as_float(uu[j].x & 0xffff0000u),  a1);
                a2 = fmaf(v, __uint_as_float(uu[j].y << 16),          a2);
                a3 = fmaf(v, __uint_as_float(uu[j].y & 0xffff0000u),  a3);
            }
        }
        for (; e < end; ++e) {
            unsigned long long p = seg[e];
            int   c = (int)(p & 0x1FFFF);
            float v = __uint_as_float((unsigned int)(p >> 32));
            uint2 u = supb[((size_t)c << 6) + lane];
            a0 = fmaf(v, __uint_as_float(u.x << 16),          a0);
            a1 = fmaf(v, __uint_as_float(u.x & 0xffff0000u),  a1);
            a2 = fmaf(v, __uint_as_float(u.y << 16),          a2);
            a3 = fmaf(v, __uint_as_float(u.y & 0xffff0000u),  a3);
        }
        // non-temporal: out (100 MB) is never re-read (f32x4 ext-vector for the builtin)
        f32x4 o;
        o[0] = a0; o[1] = a1; o[2] = a2; o[3] = a3;
        __builtin_nontemporal_store(o, (f32x4*)(out + (size_t)r * OUT_DIM) + lane);
    }
}

extern "C" void kernel_launch(void* const* d_in, const int* in_sizes, int n_in,
                              void* d_out, int out_size, void* d_ws, size_t ws_size,
                              hipStream_t stream) {
    const float* x     = (const float*)d_in[0];
    const float* W     = (const float*)d_in[1];
    const int*   erows = (const int*)d_in[2];
    const int*   ecols = (const int*)d_in[3];
    const float* evals = (const float*)d_in[4];
    const int*   activ = (const int*)d_in[5];
    float*       out   = (float*)d_out;

    const int N = in_sizes[0] / IN_DIM;   // 100000
    const int E = in_sizes[2];            // 3200000
    const int nb = (N + RPB - 1) / RPB;   // 1563 buckets

    // Workspace layout:
    //   support bf16 [N][256] | Wt bf16 [256][512] | gcur int [nb] (pad) | sorted u64 [nb][BCAP]
    char* p = (char*)d_ws;
    unsigned short* support = (unsigned short*)p;  p += (size_t)N * OUT_DIM * sizeof(unsigned short);
    __bf16* Wt      = (__bf16*)p;           p += (size_t)IN_DIM * OUT_DIM * sizeof(__bf16);
    int*    gcur    = (int*)p;              p += ((size_t)nb * sizeof(int) + 15) & ~(size_t)15;
    unsigned long long* sorted = (unsigned long long*)p;  p += (size_t)nb * BCAP * sizeof(unsigned long long);

    convert_weight<<<(IN_DIM * OUT_DIM) / 256, 256, 0, stream>>>(W, Wt);

    const int gemm_blocks = (N + 127) / 128;   // 782
    gemm_tanh<<<gemm_blocks, 512, 0, stream>>>(x, Wt, (__hip_bfloat16*)support, activ, N);

    (void)hipMemsetAsync(gcur, 0, (size_t)nb * sizeof(int), stream);

    const int sblocks = (E + SCHUNK - 1) / SCHUNK;   // 500
    bucket_scatter<<<sblocks, 512, 0, stream>>>(erows, ecols, evals, gcur, sorted, E, nb);

    bucket_accumulate<<<nb, 256, 0, stream>>>(support, gcur, sorted, out, N);
}